// Round 1
// baseline (739.659 us; speedup 1.0000x reference)
//
#include <hip/hip_runtime.h>

#define INV_SQRT2 0.7071067811865476f

typedef float f32x4 __attribute__((ext_vector_type(4)));   // native 16B vector

// global -> LDS direct staging, 16 bytes per lane.
// LDS dest is wave-uniform base + lane*16 (HW rule); global src is per-lane.
__device__ __forceinline__ void stage16(const float* g, float* l)
{
    __builtin_amdgcn_global_load_lds(
        (const __attribute__((address_space(1))) void*)g,
        (__attribute__((address_space(3))) void*)l,
        16, 0, 0);
}

// ---------------------------------------------------------------------------
// Fast path, specialized for P=2048, MU=7 (D=292, cbase=2, midT=878).
// Block = 320 threads = 4 groups x 80 (group g owns one row of the 4-row step,
// thread jv=tid%80 (<73 active) owns columns j0=4*jv..+3 — same compute
// structure as the previously-verified kernel).
//
// NEW: loads go through LDS. Each 4-row step stages 4*511 float4 "chunks"
// (row floats 2..2045, i.e. exactly cols cbase..cbase+7*D-1) via
// global_load_lds: chunk q = tid + 320*i, row gr=q/511, c=q%511,
//   global float = row*2048 + 2 + 4c   (16B-aligned: 8 + row*8192 + ... no —
//   byte = row*8192 + 8 + 16c, dword-aligned streaming, dense, each line once)
//   LDS float  = 4q                    (16B-aligned)
// Compute then reads 7 contiguous ds_read_b128 per task at
//   lds[g*2044 + k*292 + 4*jv]  (all multiples of 4 floats -> aligned,
//   consecutive lanes -> consecutive 16B -> conflict-free).
// ---------------------------------------------------------------------------
__global__ __launch_bounds__(320) void isi_main_fast(
    const float* __restrict__ dnn,
    const float* __restrict__ b,
    const float* __restrict__ h,
    const float* __restrict__ xr,
    const float* __restrict__ xi,
    const float* __restrict__ sym_r,
    const float* __restrict__ sym_i,
    const float* __restrict__ chan,
    const float* __restrict__ noise,
    const float* __restrict__ prob,
    float* __restrict__ ws,
    int B, int rowsPerBlock)
{
    constexpr int P = 2048, D = 292, midT = 878;
    constexpr int CPR = 511;              // float4 chunks per row (cols 2..2045)
    constexpr int CPS = 4 * CPR;          // 2044 chunks per 4-row step

    __shared__ float lds[CPS * 4];        // 32704 B -> 5 blocks/CU

    const int tid = threadIdx.x;
    float a0 = 0.f, a1 = 0.f, a2 = 0.f, a3 = 0.f;   // P0, P1r, P1i, P2
    float m0 = 0.f, m1 = 0.f, m2 = 0.f, m3 = 0.f;   // moment sums

    // ---- moments, grid-strided (~4.7 MB total, negligible) ----
    {
        const int gid = blockIdx.x * 320 + tid;
        const int tot = gridDim.x * 320;
        for (int i = gid; i < B; i += tot) {
            const float ch = chan[(size_t)i * 6];
            const float cr = ch * sym_r[(size_t)i * 6];
            const float ci = ch * sym_i[(size_t)i * 6];
            m0 += cr; m1 += cr * cr; m2 += ci; m3 += ci * ci;
        }
    }

    // ---- main pass ----
    const int g  = tid / 80;              // row sub-index within 4-row step
    const int jv = tid % 80;              // column-quad index
    const bool act = (jv < 73);
    const int  j0  = 4 * jv;

    f32x4 pj = (f32x4)(0.f);
    if (act) pj = *(const f32x4*)(prob + midT + j0);

    const int row0     = blockIdx.x * rowsPerBlock;
    const int waveBase = tid & ~63;       // wave-uniform

    for (int r = 0; r < rowsPerBlock; r += 4) {
        const float* stepBase = dnn + (size_t)(row0 + r) * P;

        // stage 2044 chunks: q = tid + 320*i  (i=0..5 full, i=6 tail)
#pragma unroll
        for (int i = 0; i < 6; ++i) {
            const unsigned q  = (unsigned)(tid + 320 * i);
            const unsigned gr = q / 511u;
            const unsigned c  = q - 511u * gr;
            stage16(stepBase + (size_t)gr * P + 2 + 4 * c,
                    lds + 4 * (waveBase + 320 * i));
        }
        {
            const unsigned q = (unsigned)(tid + 1920);
            if (q < (unsigned)CPS) {
                const unsigned gr = q / 511u;
                const unsigned c  = q - 511u * gr;
                stage16(stepBase + (size_t)gr * P + 2 + 4 * c,
                        lds + 4 * (waveBase + 1920));
            }
        }

        // per-row scalars (independent of staging; overlap the latency)
        const int row = row0 + r + g;
        const float bb  = b[row];
        const float bh  = bb * h[row];
        const float vxr = xr[row];
        const float vxi = xi[row];
        const float nz  = INV_SQRT2 * noise[row];
        const float cr0 = bh * vxr, ar_c = nz - vxr;
        const float ci0 = bh * vxi, ai_c = nz - vxi;

        __syncthreads();                  // drains vmcnt -> staged data visible

        if (act) {
            const float* lp = lds + g * (CPR * 4) + j0;
            const f32x4 t0 = *(const f32x4*)(lp + 0 * D);
            const f32x4 t1 = *(const f32x4*)(lp + 1 * D);
            const f32x4 t2 = *(const f32x4*)(lp + 2 * D);
            const f32x4 d0 = *(const f32x4*)(lp + 3 * D);
            const f32x4 t4 = *(const f32x4*)(lp + 4 * D);
            const f32x4 t5 = *(const f32x4*)(lp + 5 * D);
            const f32x4 t6 = *(const f32x4*)(lp + 6 * D);

            const f32x4 S = t0 + t1 + t2 + t4 + t5 + t6;   // sum7 - d0

#pragma unroll
            for (int c = 0; c < 4; ++c) {
                const float Ar = cr0 * d0[c] + ar_c;
                const float Ai = ci0 * d0[c] + ai_c;
                const float bS = bb * S[c];
                const float p  = pj[c];
                a0 += p * (Ar * Ar + Ai * Ai);
                a1 += p * (Ar * bS);
                a2 += p * (Ai * bS);
                a3 += p * (bS * bS);
            }
        }
        __syncthreads();                  // protect LDS before next stage
    }

    // ---- block reduction: 8 sums across 5 waves (reuse lds; keeps 5 blk/CU) ----
    float* red = lds;                     // 40 floats
    float v[8] = {a0, a1, a2, a3, m0, m1, m2, m3};
    const int wave = tid >> 6, lane = tid & 63;
#pragma unroll
    for (int s = 0; s < 8; ++s) {
        float x = v[s];
#pragma unroll
        for (int off = 32; off > 0; off >>= 1) x += __shfl_down(x, off, 64);
        if (lane == 0) red[s * 5 + wave] = x;
    }
    __syncthreads();
    if (tid < 8) {
        float x = red[tid * 5 + 0] + red[tid * 5 + 1] + red[tid * 5 + 2]
                + red[tid * 5 + 3] + red[tid * 5 + 4];
        ws[(size_t)blockIdx.x * 8 + tid] = x;
    }
}

// ---------------------------------------------------------------------------
// Generic fallback (runtime P/D/MU), direct-load structure, block=256.
// ---------------------------------------------------------------------------
__global__ __launch_bounds__(256) void isi_main_generic(
    const float* __restrict__ dnn,
    const float* __restrict__ b,
    const float* __restrict__ h,
    const float* __restrict__ xr,
    const float* __restrict__ xi,
    const float* __restrict__ sym_r,
    const float* __restrict__ sym_i,
    const float* __restrict__ chan,
    const float* __restrict__ noise,
    const float* __restrict__ prob,
    float* __restrict__ ws,
    int B, int P, int D, int MU, int cbase, int midT, int rowsPerBlock)
{
    const int tid = threadIdx.x;
    float a0 = 0.f, a1 = 0.f, a2 = 0.f, a3 = 0.f;
    float m0 = 0.f, m1 = 0.f, m2 = 0.f, m3 = 0.f;
    const int st = MU - 1;
    {
        const int gid = blockIdx.x * 256 + tid;
        const int tot = gridDim.x * 256;
        for (int i = gid; i < B; i += tot) {
            const float ch = chan[(size_t)i * st];
            const float cr = ch * sym_r[(size_t)i * st];
            const float ci = ch * sym_i[(size_t)i * st];
            m0 += cr; m1 += cr * cr; m2 += ci; m3 += ci * ci;
        }
    }
    const int row0 = blockIdx.x * rowsPerBlock;
    const int row1 = min(B, row0 + rowsPerBlock);
    const int nISI = MU / 2;

    for (int row = row0; row < row1; ++row) {
        const float* __restrict__ rp = dnn + (size_t)row * P;
        const float bb  = b[row];
        const float bh  = bb * h[row];
        const float vxr = xr[row];
        const float vxi = xi[row];
        const float nz  = INV_SQRT2 * noise[row];
        const float cr0 = bh * vxr, ar_c = nz - vxr;
        const float ci0 = bh * vxi, ai_c = nz - vxi;
        for (int j = tid; j < D; j += 256) {
            float sum7 = 0.f, d0 = 0.f;
            for (int k = 0; k < MU; ++k) {
                const float t = rp[cbase + k * D + j];
                sum7 += t;
                if (k == nISI) d0 = t;
            }
            const float S  = sum7 - d0;
            const float Ar = cr0 * d0 + ar_c;
            const float Ai = ci0 * d0 + ai_c;
            const float bS = bb * S;
            const float pj = prob[midT + j];
            a0 += pj * (Ar * Ar + Ai * Ai);
            a1 += pj * (Ar * bS);
            a2 += pj * (Ai * bS);
            a3 += pj * (bS * bS);
        }
    }

    __shared__ float red[8][4];
    float v[8] = {a0, a1, a2, a3, m0, m1, m2, m3};
    const int wave = tid >> 6, lane = tid & 63;
#pragma unroll
    for (int s = 0; s < 8; ++s) {
        float x = v[s];
#pragma unroll
        for (int off = 32; off > 0; off >>= 1) x += __shfl_down(x, off, 64);
        if (lane == 0) red[s][wave] = x;
    }
    __syncthreads();
    if (tid < 8) {
        float x = red[tid][0] + red[tid][1] + red[tid][2] + red[tid][3];
        ws[(size_t)blockIdx.x * 8 + tid] = x;
    }
}

// ---------------------------------------------------------------------------
// Final: one wave reduces nblk partial vectors and combines.
// ---------------------------------------------------------------------------
__global__ void isi_final(const float* __restrict__ ws,
                          float* __restrict__ out, int nblk, int B)
{
    const int lane = threadIdx.x;      // 64 threads
    float v[8] = {0.f, 0.f, 0.f, 0.f, 0.f, 0.f, 0.f, 0.f};
    for (int i = lane; i < nblk; i += 64) {
        const float* p = ws + (size_t)i * 8;
#pragma unroll
        for (int s = 0; s < 8; ++s) v[s] += p[s];
    }
#pragma unroll
    for (int s = 0; s < 8; ++s) {
        float x = v[s];
#pragma unroll
        for (int off = 32; off > 0; off >>= 1) x += __shfl_down(x, off, 64);
        v[s] = x;
    }
    if (lane == 0) {
        const float invB = 1.0f / (float)B;
        const float P0 = v[0], P1r = v[1], P1i = v[2], P2 = v[3];
        const float m1r = v[4] * invB, m2r = v[5] * invB;
        const float m1i = v[6] * invB, m2i = v[7] * invB;
        out[0] = (P0 + 2.0f * (m1r * P1r + m1i * P1i)
                  + (m2r + m2i) * P2) * invB;
    }
}

extern "C" void kernel_launch(void* const* d_in, const int* in_sizes, int n_in,
                              void* d_out, int out_size, void* d_ws, size_t ws_size,
                              hipStream_t stream)
{
    const float* dnn   = (const float*)d_in[0];
    const float* b     = (const float*)d_in[1];
    const float* h     = (const float*)d_in[2];
    const float* xr    = (const float*)d_in[3];
    const float* xi    = (const float*)d_in[4];
    const float* sym_r = (const float*)d_in[5];
    const float* sym_i = (const float*)d_in[6];
    const float* chan  = (const float*)d_in[7];
    const float* noise = (const float*)d_in[8];
    const float* prob  = (const float*)d_in[9];

    const int B  = in_sizes[1];                // 65536
    const int P  = in_sizes[0] / B;            // 2048
    const int MU = in_sizes[5] / B + 1;        // 7

    const int T     = (P / MU) / 2;            // 146
    const int D     = 2 * T;                   // 292
    const int mid   = P / 2;
    const int midT  = mid - T;                 // 878
    const int cbase = midT - (MU / 2) * D;     // 2

    if (P == 2048 && MU == 7 && D == 292 && cbase == 2 && midT == 878 &&
        (B % 8) == 0) {
        const int rowsPerBlock = 8;
        const int grid = B / rowsPerBlock;     // 8192
        isi_main_fast<<<grid, 320, 0, stream>>>(
            dnn, b, h, xr, xi, sym_r, sym_i, chan, noise, prob,
            (float*)d_ws, B, rowsPerBlock);
        isi_final<<<1, 64, 0, stream>>>((const float*)d_ws, (float*)d_out, grid, B);
    } else {
        const int rowsPerBlock = 16;
        const int grid = (B + rowsPerBlock - 1) / rowsPerBlock;
        isi_main_generic<<<grid, 256, 0, stream>>>(
            dnn, b, h, xr, xi, sym_r, sym_i, chan, noise, prob,
            (float*)d_ws, B, P, D, MU, cbase, midT, rowsPerBlock);
        isi_final<<<1, 64, 0, stream>>>((const float*)d_ws, (float*)d_out, grid, B);
    }
}

// Round 2
// 674.891 us; speedup vs baseline: 1.0960x; 1.0960x over previous
//
#include <hip/hip_runtime.h>

#define INV_SQRT2 0.7071067811865476f

typedef float f32x4 __attribute__((ext_vector_type(4)));   // native vec for nontemporal builtins

// ---------------------------------------------------------------------------
// Fast path, specialized for P=2048, MU=7 (D=292, cbase=2, midT=878).
// Block = 320 threads = 4 groups x 80. Group g owns row (rowBase + g);
// thread jv = tid%80 (<74 active) owns 4 consecutive LANE-ALIGNED columns.
//
// ALIGNMENT FIX vs the 688us version: the k-stream for output column j lives
// at float index 292k + 2 + j, so the old per-thread f32x4 loads at
// j0=4*jv sat at byte offset 8 (mod 16) -> every 16B load straddled lines.
// Now thread jv loads the ALIGNED chunk at float 292k + 4*jv (292%4==0), whose
// lane c holds logical column j = 4*jv + c - 2.  All accumulated terms carry a
// factor prob[midT+j], so the invalid edge lanes (j<0 at jv=0, j>291 at jv=73)
// are nullified by zeroing pj -- no branches, no OOB (garbage lanes read
// in-row floats 0,1,2046,2047).  Each row = 128 aligned 128B lines, once each.
//
// Loads stay nontemporal (zero reuse); no LDS in the main pass (the round-1
// LDS-staging experiment measured -53us: barrier-serialized staging loses).
// ---------------------------------------------------------------------------
__global__ __launch_bounds__(320) void isi_main_fast(
    const float* __restrict__ dnn,
    const float* __restrict__ b,
    const float* __restrict__ h,
    const float* __restrict__ xr,
    const float* __restrict__ xi,
    const float* __restrict__ sym_r,
    const float* __restrict__ sym_i,
    const float* __restrict__ chan,
    const float* __restrict__ noise,
    const float* __restrict__ prob,
    float* __restrict__ ws,
    int B, int rowsPerBlock)
{
    constexpr int P = 2048, D = 292, midT = 878;

    const int tid = threadIdx.x;
    float a0 = 0.f, a1 = 0.f, a2 = 0.f, a3 = 0.f;   // P0, P1r, P1i, P2
    float m0 = 0.f, m1 = 0.f, m2 = 0.f, m3 = 0.f;   // moment sums

    // ---- moments, grid-strided (~4.7 MB total, negligible) ----
    {
        const int gid = blockIdx.x * 320 + tid;
        const int tot = gridDim.x * 320;
        for (int i = gid; i < B; i += tot) {
            const float ch = chan[(size_t)i * 6];
            const float cr = ch * sym_r[(size_t)i * 6];
            const float ci = ch * sym_i[(size_t)i * 6];
            m0 += cr; m1 += cr * cr; m2 += ci; m3 += ci * ci;
        }
    }

    // ---- main pass ----
    const int g  = tid / 80;           // row sub-index within 4-row step
    const int jv = tid % 80;           // aligned column-quad index
    const bool act = (jv < 74);        // 74 quads cover j = -2 .. 293

    // prob factors for this thread's 4 lanes; zero for out-of-range j.
    f32x4 pj = (f32x4)(0.f);
    if (act) {
        const int jbase = 4 * jv - 2;  // logical j of lane 0
#pragma unroll
        for (int c = 0; c < 4; ++c) {
            const int j = jbase + c;
            if (j >= 0 && j < D) pj[c] = prob[midT + j];
        }
    }

    const int row0 = blockIdx.x * rowsPerBlock;

#pragma unroll 2
    for (int r = 0; r < rowsPerBlock; r += 4) {
        const int row = row0 + r + g;
        // aligned base: floats 4*jv within the row; k-stream chunk at +292k.
        const float* __restrict__ rp = dnn + (size_t)row * P + 4 * jv;

        const float bb  = b[row];
        const float bh  = bb * h[row];
        const float vxr = xr[row];
        const float vxi = xi[row];
        const float nz  = INV_SQRT2 * noise[row];
        const float cr0 = bh * vxr, ar_c = nz - vxr;
        const float ci0 = bh * vxi, ai_c = nz - vxi;

        if (act) {
            const f32x4 t0 = __builtin_nontemporal_load((const f32x4*)(rp + 0 * D));
            const f32x4 t1 = __builtin_nontemporal_load((const f32x4*)(rp + 1 * D));
            const f32x4 t2 = __builtin_nontemporal_load((const f32x4*)(rp + 2 * D));
            const f32x4 d0 = __builtin_nontemporal_load((const f32x4*)(rp + 3 * D));
            const f32x4 t4 = __builtin_nontemporal_load((const f32x4*)(rp + 4 * D));
            const f32x4 t5 = __builtin_nontemporal_load((const f32x4*)(rp + 5 * D));
            const f32x4 t6 = __builtin_nontemporal_load((const f32x4*)(rp + 6 * D));

            const f32x4 S = t0 + t1 + t2 + t4 + t5 + t6;   // sum7 - d0

#pragma unroll
            for (int c = 0; c < 4; ++c) {
                const float Ar = cr0 * d0[c] + ar_c;
                const float Ai = ci0 * d0[c] + ai_c;
                const float bS = bb * S[c];
                const float p  = pj[c];
                a0 += p * (Ar * Ar + Ai * Ai);
                a1 += p * (Ar * bS);
                a2 += p * (Ai * bS);
                a3 += p * (bS * bS);
            }
        }
    }

    // ---- block reduction: 8 sums across 5 waves ----
    __shared__ float red[8][5];
    float v[8] = {a0, a1, a2, a3, m0, m1, m2, m3};
    const int wave = tid >> 6, lane = tid & 63;
#pragma unroll
    for (int s = 0; s < 8; ++s) {
        float x = v[s];
#pragma unroll
        for (int off = 32; off > 0; off >>= 1) x += __shfl_down(x, off, 64);
        if (lane == 0) red[s][wave] = x;
    }
    __syncthreads();
    if (tid < 8) {
        float x = red[tid][0] + red[tid][1] + red[tid][2]
                + red[tid][3] + red[tid][4];
        ws[(size_t)blockIdx.x * 8 + tid] = x;
    }
}

// ---------------------------------------------------------------------------
// Generic fallback (runtime P/D/MU), direct-load structure, block=256.
// ---------------------------------------------------------------------------
__global__ __launch_bounds__(256) void isi_main_generic(
    const float* __restrict__ dnn,
    const float* __restrict__ b,
    const float* __restrict__ h,
    const float* __restrict__ xr,
    const float* __restrict__ xi,
    const float* __restrict__ sym_r,
    const float* __restrict__ sym_i,
    const float* __restrict__ chan,
    const float* __restrict__ noise,
    const float* __restrict__ prob,
    float* __restrict__ ws,
    int B, int P, int D, int MU, int cbase, int midT, int rowsPerBlock)
{
    const int tid = threadIdx.x;
    float a0 = 0.f, a1 = 0.f, a2 = 0.f, a3 = 0.f;
    float m0 = 0.f, m1 = 0.f, m2 = 0.f, m3 = 0.f;
    const int st = MU - 1;
    {
        const int gid = blockIdx.x * 256 + tid;
        const int tot = gridDim.x * 256;
        for (int i = gid; i < B; i += tot) {
            const float ch = chan[(size_t)i * st];
            const float cr = ch * sym_r[(size_t)i * st];
            const float ci = ch * sym_i[(size_t)i * st];
            m0 += cr; m1 += cr * cr; m2 += ci; m3 += ci * ci;
        }
    }
    const int row0 = blockIdx.x * rowsPerBlock;
    const int row1 = min(B, row0 + rowsPerBlock);
    const int nISI = MU / 2;

    for (int row = row0; row < row1; ++row) {
        const float* __restrict__ rp = dnn + (size_t)row * P;
        const float bb  = b[row];
        const float bh  = bb * h[row];
        const float vxr = xr[row];
        const float vxi = xi[row];
        const float nz  = INV_SQRT2 * noise[row];
        const float cr0 = bh * vxr, ar_c = nz - vxr;
        const float ci0 = bh * vxi, ai_c = nz - vxi;
        for (int j = tid; j < D; j += 256) {
            float sum7 = 0.f, d0 = 0.f;
            for (int k = 0; k < MU; ++k) {
                const float t = rp[cbase + k * D + j];
                sum7 += t;
                if (k == nISI) d0 = t;
            }
            const float S  = sum7 - d0;
            const float Ar = cr0 * d0 + ar_c;
            const float Ai = ci0 * d0 + ai_c;
            const float bS = bb * S;
            const float pj = prob[midT + j];
            a0 += pj * (Ar * Ar + Ai * Ai);
            a1 += pj * (Ar * bS);
            a2 += pj * (Ai * bS);
            a3 += pj * (bS * bS);
        }
    }

    __shared__ float red[8][4];
    float v[8] = {a0, a1, a2, a3, m0, m1, m2, m3};
    const int wave = tid >> 6, lane = tid & 63;
#pragma unroll
    for (int s = 0; s < 8; ++s) {
        float x = v[s];
#pragma unroll
        for (int off = 32; off > 0; off >>= 1) x += __shfl_down(x, off, 64);
        if (lane == 0) red[s][wave] = x;
    }
    __syncthreads();
    if (tid < 8) {
        float x = red[tid][0] + red[tid][1] + red[tid][2] + red[tid][3];
        ws[(size_t)blockIdx.x * 8 + tid] = x;
    }
}

// ---------------------------------------------------------------------------
// Final: 256 threads (4 waves) reduce nblk partial vectors and combine.
// (Old 1-wave version walked 4096x8 floats in ~64 dependent rounds over a
//  cold L2 -- ~15us of pure latency. 4 waves + deeper MLP cuts that ~4x.)
// ---------------------------------------------------------------------------
__global__ __launch_bounds__(256) void isi_final(const float* __restrict__ ws,
                                                 float* __restrict__ out,
                                                 int nblk, int B)
{
    const int tid = threadIdx.x;
    float v[8] = {0.f, 0.f, 0.f, 0.f, 0.f, 0.f, 0.f, 0.f};
    for (int i = tid; i < nblk; i += 256) {
        const float* p = ws + (size_t)i * 8;
#pragma unroll
        for (int s = 0; s < 8; ++s) v[s] += p[s];
    }
    __shared__ float red[8][4];
    const int wave = tid >> 6, lane = tid & 63;
#pragma unroll
    for (int s = 0; s < 8; ++s) {
        float x = v[s];
#pragma unroll
        for (int off = 32; off > 0; off >>= 1) x += __shfl_down(x, off, 64);
        if (lane == 0) red[s][wave] = x;
    }
    __syncthreads();
    if (tid == 0) {
        float t[8];
#pragma unroll
        for (int s = 0; s < 8; ++s)
            t[s] = red[s][0] + red[s][1] + red[s][2] + red[s][3];
        const float invB = 1.0f / (float)B;
        const float P0 = t[0], P1r = t[1], P1i = t[2], P2 = t[3];
        const float m1r = t[4] * invB, m2r = t[5] * invB;
        const float m1i = t[6] * invB, m2i = t[7] * invB;
        out[0] = (P0 + 2.0f * (m1r * P1r + m1i * P1i)
                  + (m2r + m2i) * P2) * invB;
    }
}

extern "C" void kernel_launch(void* const* d_in, const int* in_sizes, int n_in,
                              void* d_out, int out_size, void* d_ws, size_t ws_size,
                              hipStream_t stream)
{
    const float* dnn   = (const float*)d_in[0];
    const float* b     = (const float*)d_in[1];
    const float* h     = (const float*)d_in[2];
    const float* xr    = (const float*)d_in[3];
    const float* xi    = (const float*)d_in[4];
    const float* sym_r = (const float*)d_in[5];
    const float* sym_i = (const float*)d_in[6];
    const float* chan  = (const float*)d_in[7];
    const float* noise = (const float*)d_in[8];
    const float* prob  = (const float*)d_in[9];

    const int B  = in_sizes[1];                // 65536
    const int P  = in_sizes[0] / B;            // 2048
    const int MU = in_sizes[5] / B + 1;        // 7

    const int T     = (P / MU) / 2;            // 146
    const int D     = 2 * T;                   // 292
    const int mid   = P / 2;
    const int midT  = mid - T;                 // 878
    const int cbase = midT - (MU / 2) * D;     // 2

    const int rowsPerBlock = 16;
    const int grid = (B + rowsPerBlock - 1) / rowsPerBlock;   // 4096

    if (P == 2048 && MU == 7 && D == 292 && cbase == 2 && midT == 878 &&
        (B % rowsPerBlock) == 0) {
        isi_main_fast<<<grid, 320, 0, stream>>>(
            dnn, b, h, xr, xi, sym_r, sym_i, chan, noise, prob,
            (float*)d_ws, B, rowsPerBlock);
    } else {
        isi_main_generic<<<grid, 256, 0, stream>>>(
            dnn, b, h, xr, xi, sym_r, sym_i, chan, noise, prob,
            (float*)d_ws, B, P, D, MU, cbase, midT, rowsPerBlock);
    }
    isi_final<<<1, 256, 0, stream>>>((const float*)d_ws, (float*)d_out, grid, B);
}